// Round 1
// baseline (947.235 us; speedup 1.0000x reference)
//
#include <hip/hip_runtime.h>

#define N_NODES 100000
#define N_EDGES 1600000

// ---------------- CSR build: histogram -> scan -> scatter ----------------

__global__ void k_hist(const int* __restrict__ dst, int* __restrict__ cnt, int E) {
    int i = blockIdx.x * blockDim.x + threadIdx.x;
    int stride = gridDim.x * blockDim.x;
    for (; i < E; i += stride) atomicAdd(&cnt[dst[i]], 1);
}

__global__ void k_dis(const int* __restrict__ cnt, float* __restrict__ dis, int n) {
    int i = blockIdx.x * blockDim.x + threadIdx.x;
    if (i < n) dis[i] = rsqrtf((float)(cnt[i] + 1));  // deg includes self-loop
}

// per-block sums of 1024-element chunks
__global__ void k_scan1(const int* __restrict__ cnt, int* __restrict__ bsum, int n) {
    int t = threadIdx.x;
    int base = blockIdx.x * 1024 + t * 4;
    int4 v = {0, 0, 0, 0};
    if (base + 3 < n) v = *(const int4*)(cnt + base);
    else {
        if (base     < n) v.x = cnt[base];
        if (base + 1 < n) v.y = cnt[base + 1];
        if (base + 2 < n) v.z = cnt[base + 2];
    }
    int s = v.x + v.y + v.z + v.w;
    for (int off = 32; off; off >>= 1) s += __shfl_down(s, off);
    __shared__ int ws[4];
    int w = t >> 6, l = t & 63;
    if (l == 0) ws[w] = s;
    __syncthreads();
    if (t == 0) bsum[blockIdx.x] = ws[0] + ws[1] + ws[2] + ws[3];
}

// scan of block sums (nb <= 128), single block
__global__ void k_scan2(const int* __restrict__ bsum, int* __restrict__ boff, int nb,
                        int* __restrict__ row_end) {
    __shared__ int sh[128];
    int t = threadIdx.x;
    if (t < nb) sh[t] = bsum[t];
    __syncthreads();
    if (t == 0) {
        int run = 0;
        for (int b = 0; b < nb; b++) { int v = sh[b]; boff[b] = run; run += v; }
        *row_end = run;  // row_start[N] == E
    }
}

// per-block exclusive scan + add block offset -> row_start, cursor
__global__ void k_scan3(const int* __restrict__ cnt, const int* __restrict__ boff,
                        int* __restrict__ row_start, int* __restrict__ cursor, int n) {
    int t = threadIdx.x;
    int base = blockIdx.x * 1024 + t * 4;
    int4 v = {0, 0, 0, 0};
    if (base + 3 < n) v = *(const int4*)(cnt + base);
    else {
        if (base     < n) v.x = cnt[base];
        if (base + 1 < n) v.y = cnt[base + 1];
        if (base + 2 < n) v.z = cnt[base + 2];
    }
    int s = v.x + v.y + v.z + v.w;
    int l = t & 63, w = t >> 6;
    int inc = s;
    for (int off = 1; off < 64; off <<= 1) {
        int u = __shfl_up(inc, off);
        if (l >= off) inc += u;
    }
    __shared__ int ws[4];
    if (l == 63) ws[w] = inc;
    __syncthreads();
    int woff = 0;
    for (int i = 0; i < w; i++) woff += ws[i];
    int e = boff[blockIdx.x] + woff + (inc - s);  // exclusive prefix for this thread
    int vals[4] = {v.x, v.y, v.z, v.w};
    for (int j = 0; j < 4; j++) {
        if (base + j < n) { row_start[base + j] = e; cursor[base + j] = e; }
        e += vals[j];
    }
}

// bucket-fill: pairs[pos] = (src, dis[src]*dis[dst]) grouped by dst
__global__ void k_scatter(const int* __restrict__ src, const int* __restrict__ dst,
                          const float* __restrict__ dis, int* __restrict__ cursor,
                          int2* __restrict__ pairs, int E) {
    int i = blockIdx.x * blockDim.x + threadIdx.x;
    int stride = gridDim.x * blockDim.x;
    for (; i < E; i += stride) {
        int s = src[i], d = dst[i];
        float c = dis[s] * dis[d];
        int pos = atomicAdd(&cursor[d], 1);
        pairs[pos] = make_int2(s, __float_as_int(c));
    }
}

// ---------------- dense h = x @ W (fp32 vector ALU, W in LDS) ----------------
// one wave handles 64/OUT rows; lane -> (sub-row, out col)
template <int IN, int OUT>
__global__ __launch_bounds__(256) void k_gemm(const float* __restrict__ x,
                                              const float* __restrict__ W,
                                              float* __restrict__ h, int n) {
    __shared__ float Wl[IN * OUT];
    for (int i = threadIdx.x; i < IN * OUT; i += blockDim.x) Wl[i] = W[i];
    __syncthreads();
    constexpr int R = 64 / OUT;
    int wid = (blockIdx.x * blockDim.x + threadIdx.x) >> 6;
    int l = threadIdx.x & 63;
    int sub = l / OUT, c = l % OUT;
    int row = wid * R + sub;
    if (row >= n) return;
    const float* xr = x + (size_t)row * IN;
    float acc = 0.f;
#pragma unroll
    for (int k = 0; k < IN; k += 4) {
        float4 xv = *(const float4*)(xr + k);  // broadcast across the sub-group
        acc += xv.x * Wl[(k + 0) * OUT + c];
        acc += xv.y * Wl[(k + 1) * OUT + c];
        acc += xv.z * Wl[(k + 2) * OUT + c];
        acc += xv.w * Wl[(k + 3) * OUT + c];
    }
    h[(size_t)row * OUT + c] = acc;
}

// ---------------- CSR gather aggregation + self-loop + bias (+relu) ----------------
template <int OUT, bool RELU>
__global__ __launch_bounds__(256) void k_agg(const float* __restrict__ h,
                                             const int2* __restrict__ pairs,
                                             const int* __restrict__ row_start,
                                             const float* __restrict__ dis,
                                             const float* __restrict__ bias,
                                             float* __restrict__ out, int n) {
    constexpr int R = 64 / OUT;
    int wid = (blockIdx.x * blockDim.x + threadIdx.x) >> 6;
    int l = threadIdx.x & 63;
    int sub = l / OUT, c = l % OUT;
    int node = wid * R + sub;
    if (node >= n) return;
    int e0 = row_start[node], e1 = row_start[node + 1];
    float acc = 0.f;
    for (int e = e0; e < e1; e++) {
        int2 p = pairs[e];                      // broadcast load within sub-group
        float coef = __int_as_float(p.y);
        acc += coef * h[(size_t)p.x * OUT + c]; // 256B/128B coalesced gather
    }
    float dd = dis[node];
    acc += dd * dd * h[(size_t)node * OUT + c]; // self-loop
    acc += bias[c];
    if (RELU) acc = fmaxf(acc, 0.f);
    out[(size_t)node * OUT + c] = acc;
}

// ---------------- launch ----------------

extern "C" void kernel_launch(void* const* d_in, const int* in_sizes, int n_in,
                              void* d_out, int out_size, void* d_ws, size_t ws_size,
                              hipStream_t stream) {
    const float* x  = (const float*)d_in[0];
    const int*   ei = (const int*)d_in[1];   // [2, E] int32
    const float* W1 = (const float*)d_in[2];
    const float* b1 = (const float*)d_in[3];
    const float* W2 = (const float*)d_in[4];
    const float* b2 = (const float*)d_in[5];
    const float* W3 = (const float*)d_in[6];
    const float* b3 = (const float*)d_in[7];

    char* ws = (char*)d_ws;
    int*   cnt       = (int*)(ws + 0);          //  400000 B
    float* dis       = (float*)(ws + 400384);   //  400000 B
    int*   row_start = (int*)(ws + 800768);     //  400004 B
    int*   cursor    = (int*)(ws + 1201152);    //  400000 B
    int*   bsum      = (int*)(ws + 1601536);    //     392 B
    int*   boff      = (int*)(ws + 1602048);    //     392 B
    int2*  pairs     = (int2*)(ws + 1602560);   // 12.8 MB
    float* h         = (float*)(ws + 14402560); // 25.6 MB
    float* a         = (float*)(ws + 40002560); // 25.6 MB  (total ~65.6 MB)

    const int* src = ei;
    const int* dst = ei + N_EDGES;

    hipMemsetAsync(cnt, 0, N_NODES * sizeof(int), stream);
    k_hist<<<2048, 256, 0, stream>>>(dst, cnt, N_EDGES);
    k_dis<<<(N_NODES + 255) / 256, 256, 0, stream>>>(cnt, dis, N_NODES);
    int nb = (N_NODES + 1023) / 1024;  // 98
    k_scan1<<<nb, 256, 0, stream>>>(cnt, bsum, N_NODES);
    k_scan2<<<1, 128, 0, stream>>>(bsum, boff, nb, row_start + N_NODES);
    k_scan3<<<nb, 256, 0, stream>>>(cnt, boff, row_start, cursor, N_NODES);
    k_scatter<<<2048, 256, 0, stream>>>(src, dst, dis, cursor, pairs, N_EDGES);

    int blocks64 = (N_NODES + 3) / 4;  // 4 waves/block, 1 row each
    int blocks32 = (N_NODES + 7) / 8;  // 4 waves/block, 2 rows each

    // layer 1: 128 -> 64, relu
    k_gemm<128, 64><<<blocks64, 256, 0, stream>>>(x, W1, h, N_NODES);
    k_agg<64, true><<<blocks64, 256, 0, stream>>>(h, pairs, row_start, dis, b1, a, N_NODES);
    // layer 2: 64 -> 64, relu
    k_gemm<64, 64><<<blocks64, 256, 0, stream>>>(a, W2, h, N_NODES);
    k_agg<64, true><<<blocks64, 256, 0, stream>>>(h, pairs, row_start, dis, b2, a, N_NODES);
    // layer 3: 64 -> 32, no relu
    k_gemm<64, 32><<<blocks32, 256, 0, stream>>>(a, W3, h, N_NODES);
    k_agg<32, false><<<blocks32, 256, 0, stream>>>(h, pairs, row_start, dis, b3,
                                                   (float*)d_out, N_NODES);
}

// Round 3
// 838.934 us; speedup vs baseline: 1.1291x; 1.1291x over previous
//
#include <hip/hip_runtime.h>

#define N_NODES 100000
#define N_EDGES 1600000

// ---------------- CSR build: histogram -> scan -> scatter ----------------

__global__ void k_hist(const int* __restrict__ dst, int* __restrict__ cnt, int E) {
    int i = blockIdx.x * blockDim.x + threadIdx.x;
    int stride = gridDim.x * blockDim.x;
    for (; i < E; i += stride) atomicAdd(&cnt[dst[i]], 1);
}

__global__ void k_dis(const int* __restrict__ cnt, float* __restrict__ dis, int n) {
    int i = blockIdx.x * blockDim.x + threadIdx.x;
    if (i < n) dis[i] = rsqrtf((float)(cnt[i] + 1));  // deg includes self-loop
}

// per-block sums of 1024-element chunks
__global__ void k_scan1(const int* __restrict__ cnt, int* __restrict__ bsum, int n) {
    int t = threadIdx.x;
    int base = blockIdx.x * 1024 + t * 4;
    int4 v = {0, 0, 0, 0};
    if (base + 3 < n) v = *(const int4*)(cnt + base);
    else {
        if (base     < n) v.x = cnt[base];
        if (base + 1 < n) v.y = cnt[base + 1];
        if (base + 2 < n) v.z = cnt[base + 2];
    }
    int s = v.x + v.y + v.z + v.w;
    for (int off = 32; off; off >>= 1) s += __shfl_down(s, off);
    __shared__ int ws[4];
    int w = t >> 6, l = t & 63;
    if (l == 0) ws[w] = s;
    __syncthreads();
    if (t == 0) bsum[blockIdx.x] = ws[0] + ws[1] + ws[2] + ws[3];
}

// scan of block sums (nb <= 128), single block
__global__ void k_scan2(const int* __restrict__ bsum, int* __restrict__ boff, int nb,
                        int* __restrict__ row_end) {
    __shared__ int sh[128];
    int t = threadIdx.x;
    if (t < nb) sh[t] = bsum[t];
    __syncthreads();
    if (t == 0) {
        int run = 0;
        for (int b = 0; b < nb; b++) { int v = sh[b]; boff[b] = run; run += v; }
        *row_end = run;  // row_start[N] == E
    }
}

// per-block exclusive scan + add block offset -> row_start, cursor
__global__ void k_scan3(const int* __restrict__ cnt, const int* __restrict__ boff,
                        int* __restrict__ row_start, int* __restrict__ cursor, int n) {
    int t = threadIdx.x;
    int base = blockIdx.x * 1024 + t * 4;
    int4 v = {0, 0, 0, 0};
    if (base + 3 < n) v = *(const int4*)(cnt + base);
    else {
        if (base     < n) v.x = cnt[base];
        if (base + 1 < n) v.y = cnt[base + 1];
        if (base + 2 < n) v.z = cnt[base + 2];
    }
    int s = v.x + v.y + v.z + v.w;
    int l = t & 63, w = t >> 6;
    int inc = s;
    for (int off = 1; off < 64; off <<= 1) {
        int u = __shfl_up(inc, off);
        if (l >= off) inc += u;
    }
    __shared__ int ws[4];
    if (l == 63) ws[w] = inc;
    __syncthreads();
    int woff = 0;
    for (int i = 0; i < w; i++) woff += ws[i];
    int e = boff[blockIdx.x] + woff + (inc - s);  // exclusive prefix for this thread
    int vals[4] = {v.x, v.y, v.z, v.w};
    for (int j = 0; j < 4; j++) {
        if (base + j < n) { row_start[base + j] = e; cursor[base + j] = e; }
        e += vals[j];
    }
}

// bucket-fill: pairs[pos] = (src, dis[src]*dis[dst]) grouped by dst
__global__ void k_scatter(const int* __restrict__ src, const int* __restrict__ dst,
                          const float* __restrict__ dis, int* __restrict__ cursor,
                          int2* __restrict__ pairs, int E) {
    int i = blockIdx.x * blockDim.x + threadIdx.x;
    int stride = gridDim.x * blockDim.x;
    for (; i < E; i += stride) {
        int s = src[i], d = dst[i];
        float c = dis[s] * dis[d];
        int pos = atomicAdd(&cursor[d], 1);
        pairs[pos] = make_int2(s, __float_as_int(c));
    }
}

// ---------------- dense H = A @ W, register-tiled fp32 ----------------
// block = 256 threads computes BM x OUT tile; thread = 4 rows x 4 cols.
// A chunk (BM x BK) in LDS with +4 pad (16B-aligned b128 reads, <=2-way banks);
// W fully in LDS. Inner loop: 8 ds_read_b128 per 64 FMAs.
template <int IN, int OUT>
__global__ __launch_bounds__(256) void k_gemm(const float* __restrict__ A,
                                              const float* __restrict__ W,
                                              float* __restrict__ H, int n) {
    constexpr int BM = 4096 / OUT;            // 64 (OUT=64) or 128 (OUT=32)
    constexpr int BK = (IN > 64) ? 64 : IN;   // k-chunk
    constexpr int LDA = BK + 4;               // padded lds stride
    __shared__ float At[BM * LDA];
    __shared__ float Wl[IN * OUT];

    const int tid = threadIdx.x;
    // stage W (whole) once
    for (int i = tid * 4; i < IN * OUT; i += 1024)
        *(float4*)&Wl[i] = *(const float4*)&W[i];

    const int row0 = blockIdx.x * BM;
    const int tc = tid % (OUT / 4);           // col group (4 cols)
    const int tr = tid / (OUT / 4);           // row group (4 rows)

    float4 acc[4];
    acc[0] = acc[1] = acc[2] = acc[3] = make_float4(0.f, 0.f, 0.f, 0.f);

    for (int k0 = 0; k0 < IN; k0 += BK) {
        __syncthreads();                       // At reuse guard (and W ready, 1st iter)
        constexpr int TPR = BK / 4;            // float4 loads per row
        for (int f = tid; f < BM * TPR; f += 256) {
            int r = f / TPR, k4 = f % TPR;
            int grow = row0 + r;
            float4 v = make_float4(0.f, 0.f, 0.f, 0.f);
            if (grow < n) v = *(const float4*)&A[(size_t)grow * IN + k0 + k4 * 4];
            *(float4*)&At[r * LDA + k4 * 4] = v;
        }
        __syncthreads();
#pragma unroll
        for (int k4 = 0; k4 < BK / 4; k4++) {
            float4 av[4], wv[4];
#pragma unroll
            for (int i = 0; i < 4; i++)
                av[i] = *(float4*)&At[(tr * 4 + i) * LDA + k4 * 4];
#pragma unroll
            for (int j = 0; j < 4; j++)
                wv[j] = *(float4*)&Wl[(k0 + k4 * 4 + j) * OUT + tc * 4];
#pragma unroll
            for (int i = 0; i < 4; i++) {
                acc[i].x += av[i].x * wv[0].x + av[i].y * wv[1].x + av[i].z * wv[2].x + av[i].w * wv[3].x;
                acc[i].y += av[i].x * wv[0].y + av[i].y * wv[1].y + av[i].z * wv[2].y + av[i].w * wv[3].y;
                acc[i].z += av[i].x * wv[0].z + av[i].y * wv[1].z + av[i].z * wv[2].z + av[i].w * wv[3].z;
                acc[i].w += av[i].x * wv[0].w + av[i].y * wv[1].w + av[i].z * wv[2].w + av[i].w * wv[3].w;
            }
        }
    }
#pragma unroll
    for (int i = 0; i < 4; i++) {
        int grow = row0 + tr * 4 + i;
        if (grow < n) *(float4*)&H[(size_t)grow * OUT + tc * 4] = acc[i];
    }
}

// ---------------- CSR gather aggregation + self-loop + bias (+relu) ----------------
template <int OUT, bool RELU>
__global__ __launch_bounds__(256) void k_agg(const float* __restrict__ h,
                                             const int2* __restrict__ pairs,
                                             const int* __restrict__ row_start,
                                             const float* __restrict__ dis,
                                             const float* __restrict__ bias,
                                             float* __restrict__ out, int n) {
    constexpr int R = 64 / OUT;
    int wid = (blockIdx.x * blockDim.x + threadIdx.x) >> 6;
    int l = threadIdx.x & 63;
    int sub = l / OUT, c = l % OUT;
    int node = wid * R + sub;
    if (node >= n) return;
    int e0 = row_start[node], e1 = row_start[node + 1];
    float acc = 0.f;
    for (int e = e0; e < e1; e++) {
        int2 p = pairs[e];                      // broadcast load within sub-group
        float coef = __int_as_float(p.y);
        acc += coef * h[(size_t)p.x * OUT + c]; // 256B/128B coalesced gather
    }
    float dd = dis[node];
    acc += dd * dd * h[(size_t)node * OUT + c]; // self-loop
    acc += bias[c];
    if (RELU) acc = fmaxf(acc, 0.f);
    out[(size_t)node * OUT + c] = acc;
}

// ---------------- launch ----------------

extern "C" void kernel_launch(void* const* d_in, const int* in_sizes, int n_in,
                              void* d_out, int out_size, void* d_ws, size_t ws_size,
                              hipStream_t stream) {
    const float* x  = (const float*)d_in[0];
    const int*   ei = (const int*)d_in[1];   // [2, E] int32
    const float* W1 = (const float*)d_in[2];
    const float* b1 = (const float*)d_in[3];
    const float* W2 = (const float*)d_in[4];
    const float* b2 = (const float*)d_in[5];
    const float* W3 = (const float*)d_in[6];
    const float* b3 = (const float*)d_in[7];

    char* ws = (char*)d_ws;
    int*   cnt       = (int*)(ws + 0);          //  400000 B
    float* dis       = (float*)(ws + 400384);   //  400000 B
    int*   row_start = (int*)(ws + 800768);     //  400004 B
    int*   cursor    = (int*)(ws + 1201152);    //  400000 B
    int*   bsum      = (int*)(ws + 1601536);    //     392 B
    int*   boff      = (int*)(ws + 1602048);    //     392 B
    int2*  pairs     = (int2*)(ws + 1602560);   // 12.8 MB
    float* h         = (float*)(ws + 14402560); // 25.6 MB
    float* a         = (float*)(ws + 40002560); // 25.6 MB  (total ~65.6 MB)

    const int* src = ei;
    const int* dst = ei + N_EDGES;

    hipMemsetAsync(cnt, 0, N_NODES * sizeof(int), stream);
    k_hist<<<2048, 256, 0, stream>>>(dst, cnt, N_EDGES);
    k_dis<<<(N_NODES + 255) / 256, 256, 0, stream>>>(cnt, dis, N_NODES);
    int nb = (N_NODES + 1023) / 1024;  // 98
    k_scan1<<<nb, 256, 0, stream>>>(cnt, bsum, N_NODES);
    k_scan2<<<1, 128, 0, stream>>>(bsum, boff, nb, row_start + N_NODES);
    k_scan3<<<nb, 256, 0, stream>>>(cnt, boff, row_start, cursor, N_NODES);
    k_scatter<<<2048, 256, 0, stream>>>(src, dst, dis, cursor, pairs, N_EDGES);

    int gemm64 = (N_NODES + 63) / 64;    // BM=64 tiles
    int gemm32 = (N_NODES + 127) / 128;  // BM=128 tiles
    int blocks64 = (N_NODES + 3) / 4;    // agg: 4 waves/block, 1 node each
    int blocks32 = (N_NODES + 7) / 8;    // agg: 4 waves/block, 2 nodes each

    // layer 1: 128 -> 64, relu
    k_gemm<128, 64><<<gemm64, 256, 0, stream>>>(x, W1, h, N_NODES);
    k_agg<64, true><<<blocks64, 256, 0, stream>>>(h, pairs, row_start, dis, b1, a, N_NODES);
    // layer 2: 64 -> 64, relu
    k_gemm<64, 64><<<gemm64, 256, 0, stream>>>(a, W2, h, N_NODES);
    k_agg<64, true><<<blocks64, 256, 0, stream>>>(h, pairs, row_start, dis, b2, a, N_NODES);
    // layer 3: 64 -> 32, no relu
    k_gemm<64, 32><<<gemm32, 256, 0, stream>>>(a, W3, h, N_NODES);
    k_agg<32, false><<<blocks32, 256, 0, stream>>>(h, pairs, row_start, dis, b3,
                                                   (float*)d_out, N_NODES);
}

// Round 5
// 621.007 us; speedup vs baseline: 1.5253x; 1.3509x over previous
//
#include <hip/hip_runtime.h>

#define N_NODES 100000
#define N_EDGES 1600000

// ---------------- CSR build: histogram -> scan -> scatter ----------------

__global__ void k_hist(const int* __restrict__ dst, int* __restrict__ cnt, int E) {
    int i = blockIdx.x * blockDim.x + threadIdx.x;
    int stride = gridDim.x * blockDim.x;
    for (; i < E; i += stride) atomicAdd(&cnt[dst[i]], 1);
}

__global__ void k_dis(const int* __restrict__ cnt, float* __restrict__ dis, int n) {
    int i = blockIdx.x * blockDim.x + threadIdx.x;
    if (i < n) dis[i] = rsqrtf((float)(cnt[i] + 1));  // deg includes self-loop
}

// per-block sums of 1024-element chunks
__global__ void k_scan1(const int* __restrict__ cnt, int* __restrict__ bsum, int n) {
    int t = threadIdx.x;
    int base = blockIdx.x * 1024 + t * 4;
    int4 v = {0, 0, 0, 0};
    if (base + 3 < n) v = *(const int4*)(cnt + base);
    else {
        if (base     < n) v.x = cnt[base];
        if (base + 1 < n) v.y = cnt[base + 1];
        if (base + 2 < n) v.z = cnt[base + 2];
    }
    int s = v.x + v.y + v.z + v.w;
    for (int off = 32; off; off >>= 1) s += __shfl_down(s, off);
    __shared__ int ws[4];
    int w = t >> 6, l = t & 63;
    if (l == 0) ws[w] = s;
    __syncthreads();
    if (t == 0) bsum[blockIdx.x] = ws[0] + ws[1] + ws[2] + ws[3];
}

// scan of block sums (nb <= 128), single block
__global__ void k_scan2(const int* __restrict__ bsum, int* __restrict__ boff, int nb,
                        int* __restrict__ row_end) {
    __shared__ int sh[128];
    int t = threadIdx.x;
    if (t < nb) sh[t] = bsum[t];
    __syncthreads();
    if (t == 0) {
        int run = 0;
        for (int b = 0; b < nb; b++) { int v = sh[b]; boff[b] = run; run += v; }
        *row_end = run;  // row_start[N] == E
    }
}

// per-block exclusive scan + add block offset -> row_start, cursor
__global__ void k_scan3(const int* __restrict__ cnt, const int* __restrict__ boff,
                        int* __restrict__ row_start, int* __restrict__ cursor, int n) {
    int t = threadIdx.x;
    int base = blockIdx.x * 1024 + t * 4;
    int4 v = {0, 0, 0, 0};
    if (base + 3 < n) v = *(const int4*)(cnt + base);
    else {
        if (base     < n) v.x = cnt[base];
        if (base + 1 < n) v.y = cnt[base + 1];
        if (base + 2 < n) v.z = cnt[base + 2];
    }
    int s = v.x + v.y + v.z + v.w;
    int l = t & 63, w = t >> 6;
    int inc = s;
    for (int off = 1; off < 64; off <<= 1) {
        int u = __shfl_up(inc, off);
        if (l >= off) inc += u;
    }
    __shared__ int ws[4];
    if (l == 63) ws[w] = inc;
    __syncthreads();
    int woff = 0;
    for (int i = 0; i < w; i++) woff += ws[i];
    int e = boff[blockIdx.x] + woff + (inc - s);  // exclusive prefix for this thread
    int vals[4] = {v.x, v.y, v.z, v.w};
    for (int j = 0; j < 4; j++) {
        if (base + j < n) { row_start[base + j] = e; cursor[base + j] = e; }
        e += vals[j];
    }
}

// bucket-fill: pairs[pos] = (src, dis[src]*dis[dst]) grouped by dst
__global__ void k_scatter(const int* __restrict__ src, const int* __restrict__ dst,
                          const float* __restrict__ dis, int* __restrict__ cursor,
                          int2* __restrict__ pairs, int E) {
    int i = blockIdx.x * blockDim.x + threadIdx.x;
    int stride = gridDim.x * blockDim.x;
    for (; i < E; i += stride) {
        int s = src[i], d = dst[i];
        float c = dis[s] * dis[d];
        int pos = atomicAdd(&cursor[d], 1);
        pairs[pos] = make_int2(s, __float_as_int(c));
    }
}

// ---------------- dense H = A @ W, register-tiled fp32 ----------------
template <int IN, int OUT>
__global__ __launch_bounds__(256) void k_gemm(const float* __restrict__ A,
                                              const float* __restrict__ W,
                                              float* __restrict__ H, int n) {
    constexpr int BM = 4096 / OUT;            // 64 (OUT=64) or 128 (OUT=32)
    constexpr int BK = (IN > 64) ? 64 : IN;   // k-chunk
    constexpr int LDA = BK + 4;               // padded lds stride
    __shared__ float At[BM * LDA];
    __shared__ float Wl[IN * OUT];

    const int tid = threadIdx.x;
    for (int i = tid * 4; i < IN * OUT; i += 1024)
        *(float4*)&Wl[i] = *(const float4*)&W[i];

    const int row0 = blockIdx.x * BM;
    const int tc = tid % (OUT / 4);           // col group (4 cols)
    const int tr = tid / (OUT / 4);           // row group (4 rows)

    float4 acc[4];
    acc[0] = acc[1] = acc[2] = acc[3] = make_float4(0.f, 0.f, 0.f, 0.f);

    for (int k0 = 0; k0 < IN; k0 += BK) {
        __syncthreads();
        constexpr int TPR = BK / 4;
        for (int f = tid; f < BM * TPR; f += 256) {
            int r = f / TPR, k4 = f % TPR;
            int grow = row0 + r;
            float4 v = make_float4(0.f, 0.f, 0.f, 0.f);
            if (grow < n) v = *(const float4*)&A[(size_t)grow * IN + k0 + k4 * 4];
            *(float4*)&At[r * LDA + k4 * 4] = v;
        }
        __syncthreads();
#pragma unroll
        for (int k4 = 0; k4 < BK / 4; k4++) {
            float4 av[4], wv[4];
#pragma unroll
            for (int i = 0; i < 4; i++)
                av[i] = *(float4*)&At[(tr * 4 + i) * LDA + k4 * 4];
#pragma unroll
            for (int j = 0; j < 4; j++)
                wv[j] = *(float4*)&Wl[(k0 + k4 * 4 + j) * OUT + tc * 4];
#pragma unroll
            for (int i = 0; i < 4; i++) {
                acc[i].x += av[i].x * wv[0].x + av[i].y * wv[1].x + av[i].z * wv[2].x + av[i].w * wv[3].x;
                acc[i].y += av[i].x * wv[0].y + av[i].y * wv[1].y + av[i].z * wv[2].y + av[i].w * wv[3].y;
                acc[i].z += av[i].x * wv[0].z + av[i].y * wv[1].z + av[i].z * wv[2].z + av[i].w * wv[3].z;
                acc[i].w += av[i].x * wv[0].w + av[i].y * wv[1].w + av[i].z * wv[2].w + av[i].w * wv[3].w;
            }
        }
    }
#pragma unroll
    for (int i = 0; i < 4; i++) {
        int grow = row0 + tr * 4 + i;
        if (grow < n) *(float4*)&H[(size_t)grow * OUT + tc * 4] = acc[i];
    }
}

// ---------------- CSR gather aggregation, MLP-widened ----------------
// One wave per node. Per batch, GROUPS=256/OUT edges are gathered in ONE load
// instruction: each group of LPG=OUT/4 lanes loads float4 of one edge's h-row.
// Unrolled x2 -> 2*GROUPS edges (2KB) in flight per wave. Tail is branch-free
// (clamped index, zeroed coef). End: log2(GROUPS) shfl_xor rounds on float4.
template <int OUT, bool RELU>
__global__ __launch_bounds__(256) void k_agg(const float* __restrict__ h,
                                             const int2* __restrict__ pairs,
                                             const int* __restrict__ row_start,
                                             const float* __restrict__ dis,
                                             const float* __restrict__ bias,
                                             float* __restrict__ out, int n) {
    constexpr int GROUPS = 256 / OUT;   // edges per batch (64->4, 32->8)
    constexpr int LPG = OUT / 4;        // lanes per edge group
    int node = (blockIdx.x * blockDim.x + threadIdx.x) >> 6;  // wave id
    if (node >= n) return;
    int l = threadIdx.x & 63;
    int u = l / LPG;                    // edge slot in batch
    int c = (l % LPG) * 4;              // col (float4)
    int e0 = row_start[node], e1 = row_start[node + 1];

    float4 acc = make_float4(0.f, 0.f, 0.f, 0.f);
    for (int e = e0; e < e1; e += 2 * GROUPS) {
        // batch A
        int ia = e + u;
        bool va = ia < e1;
        int2 pa = pairs[va ? ia : e0];
        float ca = va ? __int_as_float(pa.y) : 0.f;
        float4 ha = *(const float4*)&h[(size_t)pa.x * OUT + c];
        // batch B
        int ib = e + GROUPS + u;
        bool vb = ib < e1;
        int2 pb = pairs[vb ? ib : e0];
        float cb = vb ? __int_as_float(pb.y) : 0.f;
        float4 hb = *(const float4*)&h[(size_t)pb.x * OUT + c];

        acc.x += ca * ha.x + cb * hb.x;
        acc.y += ca * ha.y + cb * hb.y;
        acc.z += ca * ha.z + cb * hb.z;
        acc.w += ca * ha.w + cb * hb.w;
    }
#pragma unroll
    for (int m = LPG; m < 64; m <<= 1) {
        acc.x += __shfl_xor(acc.x, m);
        acc.y += __shfl_xor(acc.y, m);
        acc.z += __shfl_xor(acc.z, m);
        acc.w += __shfl_xor(acc.w, m);
    }
    if (l < LPG) {
        float dd = dis[node];
        float s = dd * dd;
        float4 hv = *(const float4*)&h[(size_t)node * OUT + c];
        float4 bv = *(const float4*)&bias[c];
        acc.x += s * hv.x + bv.x;
        acc.y += s * hv.y + bv.y;
        acc.z += s * hv.z + bv.z;
        acc.w += s * hv.w + bv.w;
        if (RELU) {
            acc.x = fmaxf(acc.x, 0.f); acc.y = fmaxf(acc.y, 0.f);
            acc.z = fmaxf(acc.z, 0.f); acc.w = fmaxf(acc.w, 0.f);
        }
        *(float4*)&out[(size_t)node * OUT + c] = acc;
    }
}

// ---------------- launch ----------------

extern "C" void kernel_launch(void* const* d_in, const int* in_sizes, int n_in,
                              void* d_out, int out_size, void* d_ws, size_t ws_size,
                              hipStream_t stream) {
    const float* x  = (const float*)d_in[0];
    const int*   ei = (const int*)d_in[1];   // [2, E] int32
    const float* W1 = (const float*)d_in[2];
    const float* b1 = (const float*)d_in[3];
    const float* W2 = (const float*)d_in[4];
    const float* b2 = (const float*)d_in[5];
    const float* W3 = (const float*)d_in[6];
    const float* b3 = (const float*)d_in[7];

    char* ws = (char*)d_ws;
    int*   cnt       = (int*)(ws + 0);          //  400000 B
    float* dis       = (float*)(ws + 400384);   //  400000 B
    int*   row_start = (int*)(ws + 800768);     //  400004 B
    int*   cursor    = (int*)(ws + 1201152);    //  400000 B
    int*   bsum      = (int*)(ws + 1601536);    //     392 B
    int*   boff      = (int*)(ws + 1602048);    //     392 B
    int2*  pairs     = (int2*)(ws + 1602560);   // 12.8 MB
    float* h         = (float*)(ws + 14402560); // 25.6 MB
    float* a         = (float*)(ws + 40002560); // 25.6 MB  (total ~65.6 MB)

    const int* src = ei;
    const int* dst = ei + N_EDGES;

    hipMemsetAsync(cnt, 0, N_NODES * sizeof(int), stream);
    k_hist<<<2048, 256, 0, stream>>>(dst, cnt, N_EDGES);
    k_dis<<<(N_NODES + 255) / 256, 256, 0, stream>>>(cnt, dis, N_NODES);
    int nb = (N_NODES + 1023) / 1024;  // 98
    k_scan1<<<nb, 256, 0, stream>>>(cnt, bsum, N_NODES);
    k_scan2<<<1, 128, 0, stream>>>(bsum, boff, nb, row_start + N_NODES);
    k_scan3<<<nb, 256, 0, stream>>>(cnt, boff, row_start, cursor, N_NODES);
    k_scatter<<<2048, 256, 0, stream>>>(src, dst, dis, cursor, pairs, N_EDGES);

    int gemm64 = (N_NODES + 63) / 64;      // BM=64 tiles
    int gemm32 = (N_NODES + 127) / 128;    // BM=128 tiles
    int aggblk = (N_NODES + 3) / 4;        // 1 node per wave, 4 waves/block

    // layer 1: 128 -> 64, relu
    k_gemm<128, 64><<<gemm64, 256, 0, stream>>>(x, W1, h, N_NODES);
    k_agg<64, true><<<aggblk, 256, 0, stream>>>(h, pairs, row_start, dis, b1, a, N_NODES);
    // layer 2: 64 -> 64, relu
    k_gemm<64, 64><<<gemm64, 256, 0, stream>>>(a, W2, h, N_NODES);
    k_agg<64, true><<<aggblk, 256, 0, stream>>>(h, pairs, row_start, dis, b2, a, N_NODES);
    // layer 3: 64 -> 32, no relu
    k_gemm<64, 32><<<gemm32, 256, 0, stream>>>(a, W3, h, N_NODES);
    k_agg<32, false><<<aggblk, 256, 0, stream>>>(h, pairs, row_start, dis, b3,
                                                 (float*)d_out, N_NODES);
}

// Round 6
// 526.319 us; speedup vs baseline: 1.7997x; 1.1799x over previous
//
#include <hip/hip_runtime.h>

#define N_NODES 100000
#define N_EDGES 1600000
#define NB ((N_NODES + 255) >> 8)   // 391 buckets of 256 nodes

// ---------------- CSR build: bucket hist -> scan -> 2-level scatter ----------------

// per-chunk LDS histogram over dst>>8, merged globally
__global__ __launch_bounds__(256) void k_bhist(const int* __restrict__ dst,
                                               int* __restrict__ bucket_cnt, int E) {
    __shared__ int h[NB];
    for (int i = threadIdx.x; i < NB; i += 256) h[i] = 0;
    __syncthreads();
    int c0 = blockIdx.x * 4096, c1 = min(c0 + 4096, E);
    for (int i = c0 + threadIdx.x; i < c1; i += 256)
        atomicAdd(&h[dst[i] >> 8], 1);
    __syncthreads();
    for (int i = threadIdx.x; i < NB; i += 256)
        if (h[i]) atomicAdd(&bucket_cnt[i], h[i]);
}

// serial scan of NB bucket counts -> bases + write cursors; row_start[N]=E
__global__ void k_bscan(const int* __restrict__ bucket_cnt, int* __restrict__ bucket_base,
                        int* __restrict__ bcur, int* __restrict__ row_start) {
    if (threadIdx.x == 0) {
        int run = 0;
        for (int b = 0; b < NB; b++) {
            bucket_base[b] = run; bcur[b] = run; run += bucket_cnt[b];
        }
        bucket_base[NB] = run;
        row_start[N_NODES] = run;   // == E
    }
}

// partition edges into bucket-major stage[] with block-level reservations:
// each (block,bucket) range is written densely by ONE block -> low write amp
__global__ __launch_bounds__(256) void k_partA(const int* __restrict__ src,
                                               const int* __restrict__ dst,
                                               int* __restrict__ bcur,
                                               int2* __restrict__ stage, int E) {
    __shared__ int h[NB];
    __shared__ int cur[NB];
    for (int i = threadIdx.x; i < NB; i += 256) h[i] = 0;
    __syncthreads();
    int c0 = blockIdx.x * 4096, c1 = min(c0 + 4096, E);
    for (int i = c0 + threadIdx.x; i < c1; i += 256)
        atomicAdd(&h[dst[i] >> 8], 1);
    __syncthreads();
    for (int b = threadIdx.x; b < NB; b += 256) {
        int c = h[b];
        cur[b] = c ? atomicAdd(&bcur[b], c) : 0;
    }
    __syncthreads();
    for (int i = c0 + threadIdx.x; i < c1; i += 256) {
        int s = src[i], d = dst[i];
        int pos = atomicAdd(&cur[d >> 8], 1);
        stage[pos] = make_int2(s, d);
    }
}

// one block per bucket: per-dst counts -> row_start + dis (replaces hist/dis/scans)
__global__ __launch_bounds__(256) void k_partB1(const int2* __restrict__ stage,
                                                const int* __restrict__ bucket_base,
                                                int* __restrict__ row_start,
                                                float* __restrict__ dis) {
    __shared__ int cnt[256];
    __shared__ int pref[256];
    int b = blockIdx.x;
    int node0 = b << 8;
    int nn = min(256, N_NODES - node0);
    int t = threadIdx.x;
    cnt[t] = 0;
    __syncthreads();
    int e0 = bucket_base[b], e1 = bucket_base[b + 1];
    for (int e = e0 + t; e < e1; e += 256)
        atomicAdd(&cnt[stage[e].y & 255], 1);
    __syncthreads();
    if (t == 0) {
        int run = e0;   // global CSR offset
        for (int i = 0; i < nn; i++) { pref[i] = run; run += cnt[i]; }
    }
    __syncthreads();
    if (t < nn) {
        row_start[node0 + t] = pref[t];
        dis[node0 + t] = rsqrtf((float)(cnt[t] + 1));  // deg includes self-loop
    }
}

// one block per bucket: scatter (src, coef) into the bucket's contiguous pairs
// region via LDS cursors -> single-XCD dense writes
__global__ __launch_bounds__(256) void k_partB2(const int2* __restrict__ stage,
                                                const int* __restrict__ bucket_base,
                                                const int* __restrict__ row_start,
                                                const float* __restrict__ dis,
                                                int2* __restrict__ pairs) {
    __shared__ int cur[256];
    int b = blockIdx.x;
    int node0 = b << 8;
    int nn = min(256, N_NODES - node0);
    int t = threadIdx.x;
    if (t < nn) cur[t] = row_start[node0 + t];
    __syncthreads();
    int e0 = bucket_base[b], e1 = bucket_base[b + 1];
    for (int e = e0 + t; e < e1; e += 256) {
        int2 sd = stage[e];
        float c = dis[sd.x] * dis[sd.y];
        int pos = atomicAdd(&cur[sd.y & 255], 1);
        pairs[pos] = make_int2(sd.x, __float_as_int(c));
    }
}

// ---------------- dense H = A @ W, register-tiled fp32 ----------------
template <int IN, int OUT>
__global__ __launch_bounds__(256) void k_gemm(const float* __restrict__ A,
                                              const float* __restrict__ W,
                                              float* __restrict__ H, int n) {
    constexpr int BM = 4096 / OUT;            // 64 (OUT=64) or 128 (OUT=32)
    constexpr int BK = (IN > 64) ? 64 : IN;   // k-chunk
    constexpr int LDA = BK + 4;               // padded lds stride
    __shared__ float At[BM * LDA];
    __shared__ float Wl[IN * OUT];

    const int tid = threadIdx.x;
    for (int i = tid * 4; i < IN * OUT; i += 1024)
        *(float4*)&Wl[i] = *(const float4*)&W[i];

    const int row0 = blockIdx.x * BM;
    const int tc = tid % (OUT / 4);           // col group (4 cols)
    const int tr = tid / (OUT / 4);           // row group (4 rows)

    float4 acc[4];
    acc[0] = acc[1] = acc[2] = acc[3] = make_float4(0.f, 0.f, 0.f, 0.f);

    for (int k0 = 0; k0 < IN; k0 += BK) {
        __syncthreads();
        constexpr int TPR = BK / 4;
        for (int f = tid; f < BM * TPR; f += 256) {
            int r = f / TPR, k4 = f % TPR;
            int grow = row0 + r;
            float4 v = make_float4(0.f, 0.f, 0.f, 0.f);
            if (grow < n) v = *(const float4*)&A[(size_t)grow * IN + k0 + k4 * 4];
            *(float4*)&At[r * LDA + k4 * 4] = v;
        }
        __syncthreads();
#pragma unroll
        for (int k4 = 0; k4 < BK / 4; k4++) {
            float4 av[4], wv[4];
#pragma unroll
            for (int i = 0; i < 4; i++)
                av[i] = *(float4*)&At[(tr * 4 + i) * LDA + k4 * 4];
#pragma unroll
            for (int j = 0; j < 4; j++)
                wv[j] = *(float4*)&Wl[(k0 + k4 * 4 + j) * OUT + tc * 4];
#pragma unroll
            for (int i = 0; i < 4; i++) {
                acc[i].x += av[i].x * wv[0].x + av[i].y * wv[1].x + av[i].z * wv[2].x + av[i].w * wv[3].x;
                acc[i].y += av[i].x * wv[0].y + av[i].y * wv[1].y + av[i].z * wv[2].y + av[i].w * wv[3].y;
                acc[i].z += av[i].x * wv[0].z + av[i].y * wv[1].z + av[i].z * wv[2].z + av[i].w * wv[3].z;
                acc[i].w += av[i].x * wv[0].w + av[i].y * wv[1].w + av[i].z * wv[2].w + av[i].w * wv[3].w;
            }
        }
    }
#pragma unroll
    for (int i = 0; i < 4; i++) {
        int grow = row0 + tr * 4 + i;
        if (grow < n) *(float4*)&H[(size_t)grow * OUT + tc * 4] = acc[i];
    }
}

// ---------------- CSR gather aggregation, MLP-widened ----------------
template <int OUT, bool RELU>
__global__ __launch_bounds__(256) void k_agg(const float* __restrict__ h,
                                             const int2* __restrict__ pairs,
                                             const int* __restrict__ row_start,
                                             const float* __restrict__ dis,
                                             const float* __restrict__ bias,
                                             float* __restrict__ out, int n) {
    constexpr int GROUPS = 256 / OUT;   // edges per batch (64->4, 32->8)
    constexpr int LPG = OUT / 4;        // lanes per edge group
    int node = (blockIdx.x * blockDim.x + threadIdx.x) >> 6;  // wave id
    if (node >= n) return;
    int l = threadIdx.x & 63;
    int u = l / LPG;                    // edge slot in batch
    int c = (l % LPG) * 4;              // col (float4)
    int e0 = row_start[node], e1 = row_start[node + 1];

    float4 acc = make_float4(0.f, 0.f, 0.f, 0.f);
    for (int e = e0; e < e1; e += 2 * GROUPS) {
        // batch A
        int ia = e + u;
        bool va = ia < e1;
        int2 pa = pairs[va ? ia : e0];
        float ca = va ? __int_as_float(pa.y) : 0.f;
        float4 ha = *(const float4*)&h[(size_t)pa.x * OUT + c];
        // batch B
        int ib = e + GROUPS + u;
        bool vb = ib < e1;
        int2 pb = pairs[vb ? ib : e0];
        float cb = vb ? __int_as_float(pb.y) : 0.f;
        float4 hb = *(const float4*)&h[(size_t)pb.x * OUT + c];

        acc.x += ca * ha.x + cb * hb.x;
        acc.y += ca * ha.y + cb * hb.y;
        acc.z += ca * ha.z + cb * hb.z;
        acc.w += ca * ha.w + cb * hb.w;
    }
#pragma unroll
    for (int m = LPG; m < 64; m <<= 1) {
        acc.x += __shfl_xor(acc.x, m);
        acc.y += __shfl_xor(acc.y, m);
        acc.z += __shfl_xor(acc.z, m);
        acc.w += __shfl_xor(acc.w, m);
    }
    if (l < LPG) {
        float dd = dis[node];
        float s = dd * dd;
        float4 hv = *(const float4*)&h[(size_t)node * OUT + c];
        float4 bv = *(const float4*)&bias[c];
        acc.x += s * hv.x + bv.x;
        acc.y += s * hv.y + bv.y;
        acc.z += s * hv.z + bv.z;
        acc.w += s * hv.w + bv.w;
        if (RELU) {
            acc.x = fmaxf(acc.x, 0.f); acc.y = fmaxf(acc.y, 0.f);
            acc.z = fmaxf(acc.z, 0.f); acc.w = fmaxf(acc.w, 0.f);
        }
        *(float4*)&out[(size_t)node * OUT + c] = acc;
    }
}

// ---------------- launch ----------------

extern "C" void kernel_launch(void* const* d_in, const int* in_sizes, int n_in,
                              void* d_out, int out_size, void* d_ws, size_t ws_size,
                              hipStream_t stream) {
    const float* x  = (const float*)d_in[0];
    const int*   ei = (const int*)d_in[1];   // [2, E] int32
    const float* W1 = (const float*)d_in[2];
    const float* b1 = (const float*)d_in[3];
    const float* W2 = (const float*)d_in[4];
    const float* b2 = (const float*)d_in[5];
    const float* W3 = (const float*)d_in[6];
    const float* b3 = (const float*)d_in[7];

    char* ws = (char*)d_ws;
    int*   bucket_cnt  = (int*)(ws + 0);         // 392*4 B
    int*   bucket_base = (int*)(ws + 2048);      // 392*4 B
    int*   bcur        = (int*)(ws + 4096);      // 392*4 B
    float* dis         = (float*)(ws + 8192);    // 400000 B
    int*   row_start   = (int*)(ws + 408576);    // 400004 B
    int2*  pairs       = (int2*)(ws + 809472);   // 12.8 MB
    float* h           = (float*)(ws + 13609472);// 25.6 MB
    int2*  stage       = (int2*)(ws + 13609472); // aliases h (consumed before gemm1)
    float* a           = (float*)(ws + 39209472);// 25.6 MB  (total ~64.8 MB)

    const int* src = ei;
    const int* dst = ei + N_EDGES;

    int echunks = (N_EDGES + 4095) / 4096;   // 391

    hipMemsetAsync(bucket_cnt, 0, (NB + 1) * sizeof(int), stream);
    k_bhist<<<echunks, 256, 0, stream>>>(dst, bucket_cnt, N_EDGES);
    k_bscan<<<1, 64, 0, stream>>>(bucket_cnt, bucket_base, bcur, row_start);
    k_partA<<<echunks, 256, 0, stream>>>(src, dst, bcur, stage, N_EDGES);
    k_partB1<<<NB, 256, 0, stream>>>(stage, bucket_base, row_start, dis);
    k_partB2<<<NB, 256, 0, stream>>>(stage, bucket_base, row_start, dis, pairs);

    int gemm64 = (N_NODES + 63) / 64;      // BM=64 tiles
    int gemm32 = (N_NODES + 127) / 128;    // BM=128 tiles
    int aggblk = (N_NODES + 3) / 4;        // 1 node per wave, 4 waves/block

    // layer 1: 128 -> 64, relu
    k_gemm<128, 64><<<gemm64, 256, 0, stream>>>(x, W1, h, N_NODES);
    k_agg<64, true><<<aggblk, 256, 0, stream>>>(h, pairs, row_start, dis, b1, a, N_NODES);
    // layer 2: 64 -> 64, relu
    k_gemm<64, 64><<<gemm64, 256, 0, stream>>>(a, W2, h, N_NODES);
    k_agg<64, true><<<aggblk, 256, 0, stream>>>(h, pairs, row_start, dis, b2, a, N_NODES);
    // layer 3: 64 -> 32, no relu
    k_gemm<64, 32><<<gemm32, 256, 0, stream>>>(a, W3, h, N_NODES);
    k_agg<32, false><<<aggblk, 256, 0, stream>>>(h, pairs, row_start, dis, b3,
                                                 (float*)d_out, N_NODES);
}

// Round 9
// 437.273 us; speedup vs baseline: 2.1662x; 1.2036x over previous
//
#include <hip/hip_runtime.h>

#define N_NODES 100000
#define N_EDGES 1600000
#define NB ((N_NODES + 255) >> 8)   // 391 buckets of 256 nodes

// ---------------- CSR build: bucket hist -> scan -> 2-level scatter ----------------

// per-chunk LDS histogram over dst>>8, merged globally
__global__ __launch_bounds__(256) void k_bhist(const int* __restrict__ dst,
                                               int* __restrict__ bucket_cnt, int E) {
    __shared__ int h[NB];
    for (int i = threadIdx.x; i < NB; i += 256) h[i] = 0;
    __syncthreads();
    int c0 = blockIdx.x * 4096, c1 = min(c0 + 4096, E);
    for (int i = c0 + threadIdx.x; i < c1; i += 256)
        atomicAdd(&h[dst[i] >> 8], 1);
    __syncthreads();
    for (int i = threadIdx.x; i < NB; i += 256)
        if (h[i]) atomicAdd(&bucket_cnt[i], h[i]);
}

// serial scan of NB bucket counts -> bases + write cursors; row_start[N]=E
__global__ void k_bscan(const int* __restrict__ bucket_cnt, int* __restrict__ bucket_base,
                        int* __restrict__ bcur, int* __restrict__ row_start) {
    if (threadIdx.x == 0) {
        int run = 0;
        for (int b = 0; b < NB; b++) {
            bucket_base[b] = run; bcur[b] = run; run += bucket_cnt[b];
        }
        bucket_base[NB] = run;
        row_start[N_NODES] = run;   // == E
    }
}

// partition edges into bucket-major stage[] with block-level reservations:
// each (block,bucket) range is written densely by ONE block -> low write amp
__global__ __launch_bounds__(256) void k_partA(const int* __restrict__ src,
                                               const int* __restrict__ dst,
                                               int* __restrict__ bcur,
                                               int2* __restrict__ stage, int E) {
    __shared__ int h[NB];
    __shared__ int cur[NB];
    for (int i = threadIdx.x; i < NB; i += 256) h[i] = 0;
    __syncthreads();
    int c0 = blockIdx.x * 4096, c1 = min(c0 + 4096, E);
    for (int i = c0 + threadIdx.x; i < c1; i += 256)
        atomicAdd(&h[dst[i] >> 8], 1);
    __syncthreads();
    for (int b = threadIdx.x; b < NB; b += 256) {
        int c = h[b];
        cur[b] = c ? atomicAdd(&bcur[b], c) : 0;
    }
    __syncthreads();
    for (int i = c0 + threadIdx.x; i < c1; i += 256) {
        int s = src[i], d = dst[i];
        int pos = atomicAdd(&cur[d >> 8], 1);
        stage[pos] = make_int2(s, d);
    }
}

// one block per bucket: per-dst counts -> row_start + dis (replaces hist/dis/scans)
__global__ __launch_bounds__(256) void k_partB1(const int2* __restrict__ stage,
                                                const int* __restrict__ bucket_base,
                                                int* __restrict__ row_start,
                                                float* __restrict__ dis) {
    __shared__ int cnt[256];
    __shared__ int pref[256];
    int b = blockIdx.x;
    int node0 = b << 8;
    int nn = min(256, N_NODES - node0);
    int t = threadIdx.x;
    cnt[t] = 0;
    __syncthreads();
    int e0 = bucket_base[b], e1 = bucket_base[b + 1];
    for (int e = e0 + t; e < e1; e += 256)
        atomicAdd(&cnt[stage[e].y & 255], 1);
    __syncthreads();
    if (t == 0) {
        int run = e0;   // global CSR offset
        for (int i = 0; i < nn; i++) { pref[i] = run; run += cnt[i]; }
    }
    __syncthreads();
    if (t < nn) {
        row_start[node0 + t] = pref[t];
        dis[node0 + t] = rsqrtf((float)(cnt[t] + 1));  // deg includes self-loop
    }
}

// one block per bucket: scatter (src, coef) into the bucket's contiguous pairs
// region via LDS cursors -> single-XCD dense writes
__global__ __launch_bounds__(256) void k_partB2(const int2* __restrict__ stage,
                                                const int* __restrict__ bucket_base,
                                                const int* __restrict__ row_start,
                                                const float* __restrict__ dis,
                                                int2* __restrict__ pairs) {
    __shared__ int cur[256];
    int b = blockIdx.x;
    int node0 = b << 8;
    int nn = min(256, N_NODES - node0);
    int t = threadIdx.x;
    if (t < nn) cur[t] = row_start[node0 + t];
    __syncthreads();
    int e0 = bucket_base[b], e1 = bucket_base[b + 1];
    for (int e = e0 + t; e < e1; e += 256) {
        int2 sd = stage[e];
        float c = dis[sd.x] * dis[sd.y];
        int pos = atomicAdd(&cur[sd.y & 255], 1);
        pairs[pos] = make_int2(sd.x, __float_as_int(c));
    }
}

// ---------------- dense H = A @ W: W in LDS, A direct global->reg ----------------
// 256 threads, thread = 4 rows x 4 cols. 16-lane groups share A-row addresses ->
// wave-level broadcast loads, A-tile (<=32KB) L1-resident. No per-chunk staging
// or syncs; inner loop = 4 global b128 (L1-hit) + 4 ds_read_b128 per 64 FMAs.
template <int IN, int OUT>
__global__ __launch_bounds__(256) void k_gemm(const float* __restrict__ A,
                                              const float* __restrict__ W,
                                              float* __restrict__ H, int n) {
    constexpr int BM = 1024 / (OUT / 4);      // 64 (OUT=64) or 128 (OUT=32)
    __shared__ float Wl[IN * OUT];
    const int tid = threadIdx.x;
    for (int i = tid * 4; i < IN * OUT; i += 1024)
        *(float4*)&Wl[i] = *(const float4*)&W[i];
    __syncthreads();

    const int row0 = blockIdx.x * BM;
    const int tc = tid % (OUT / 4);           // col group (4 cols)
    const int tr = tid / (OUT / 4);           // row group (4 rows)

    const float* ar[4];
    int row[4];
#pragma unroll
    for (int i = 0; i < 4; i++) {
        row[i] = row0 + tr * 4 + i;
        ar[i] = A + (size_t)min(row[i], n - 1) * IN;   // clamped, store-guarded
    }

    float4 acc[4];
    acc[0] = acc[1] = acc[2] = acc[3] = make_float4(0.f, 0.f, 0.f, 0.f);

#pragma unroll 4
    for (int k4 = 0; k4 < IN / 4; k4++) {
        float4 av[4], wv[4];
#pragma unroll
        for (int i = 0; i < 4; i++)
            av[i] = *(const float4*)(ar[i] + k4 * 4);          // broadcast in wave
#pragma unroll
        for (int j = 0; j < 4; j++)
            wv[j] = *(float4*)&Wl[(k4 * 4 + j) * OUT + tc * 4]; // conflict-free
#pragma unroll
        for (int i = 0; i < 4; i++) {
            acc[i].x += av[i].x * wv[0].x + av[i].y * wv[1].x + av[i].z * wv[2].x + av[i].w * wv[3].x;
            acc[i].y += av[i].x * wv[0].y + av[i].y * wv[1].y + av[i].z * wv[2].y + av[i].w * wv[3].y;
            acc[i].z += av[i].x * wv[0].z + av[i].y * wv[1].z + av[i].z * wv[2].z + av[i].w * wv[3].z;
            acc[i].w += av[i].x * wv[0].w + av[i].y * wv[1].w + av[i].z * wv[2].w + av[i].w * wv[3].w;
        }
    }
#pragma unroll
    for (int i = 0; i < 4; i++)
        if (row[i] < n) *(float4*)&H[(size_t)row[i] * OUT + tc * 4] = acc[i];
}

// ---------------- CSR gather aggregation, MLP-widened ----------------
template <int OUT, bool RELU>
__global__ __launch_bounds__(256) void k_agg(const float* __restrict__ h,
                                             const int2* __restrict__ pairs,
                                             const int* __restrict__ row_start,
                                             const float* __restrict__ dis,
                                             const float* __restrict__ bias,
                                             float* __restrict__ out, int n) {
    constexpr int GROUPS = 256 / OUT;   // edges per batch (64->4, 32->8)
    constexpr int LPG = OUT / 4;        // lanes per edge group
    int node = (blockIdx.x * blockDim.x + threadIdx.x) >> 6;  // wave id
    if (node >= n) return;
    int l = threadIdx.x & 63;
    int u = l / LPG;                    // edge slot in batch
    int c = (l % LPG) * 4;              // col (float4)
    int e0 = row_start[node], e1 = row_start[node + 1];

    float4 acc = make_float4(0.f, 0.f, 0.f, 0.f);
    for (int e = e0; e < e1; e += 2 * GROUPS) {
        // batch A
        int ia = e + u;
        bool va = ia < e1;
        int2 pa = pairs[va ? ia : e0];
        float ca = va ? __int_as_float(pa.y) : 0.f;
        float4 ha = *(const float4*)&h[(size_t)pa.x * OUT + c];
        // batch B
        int ib = e + GROUPS + u;
        bool vb = ib < e1;
        int2 pb = pairs[vb ? ib : e0];
        float cb = vb ? __int_as_float(pb.y) : 0.f;
        float4 hb = *(const float4*)&h[(size_t)pb.x * OUT + c];

        acc.x += ca * ha.x + cb * hb.x;
        acc.y += ca * ha.y + cb * hb.y;
        acc.z += ca * ha.z + cb * hb.z;
        acc.w += ca * ha.w + cb * hb.w;
    }
#pragma unroll
    for (int m = LPG; m < 64; m <<= 1) {
        acc.x += __shfl_xor(acc.x, m);
        acc.y += __shfl_xor(acc.y, m);
        acc.z += __shfl_xor(acc.z, m);
        acc.w += __shfl_xor(acc.w, m);
    }
    if (l < LPG) {
        float dd = dis[node];
        float s = dd * dd;
        float4 hv = *(const float4*)&h[(size_t)node * OUT + c];
        float4 bv = *(const float4*)&bias[c];
        acc.x += s * hv.x + bv.x;
        acc.y += s * hv.y + bv.y;
        acc.z += s * hv.z + bv.z;
        acc.w += s * hv.w + bv.w;
        if (RELU) {
            acc.x = fmaxf(acc.x, 0.f); acc.y = fmaxf(acc.y, 0.f);
            acc.z = fmaxf(acc.z, 0.f); acc.w = fmaxf(acc.w, 0.f);
        }
        *(float4*)&out[(size_t)node * OUT + c] = acc;
    }
}

// ---------------- launch ----------------

extern "C" void kernel_launch(void* const* d_in, const int* in_sizes, int n_in,
                              void* d_out, int out_size, void* d_ws, size_t ws_size,
                              hipStream_t stream) {
    const float* x  = (const float*)d_in[0];
    const int*   ei = (const int*)d_in[1];   // [2, E] int32
    const float* W1 = (const float*)d_in[2];
    const float* b1 = (const float*)d_in[3];
    const float* W2 = (const float*)d_in[4];
    const float* b2 = (const float*)d_in[5];
    const float* W3 = (const float*)d_in[6];
    const float* b3 = (const float*)d_in[7];

    char* ws = (char*)d_ws;
    int*   bucket_cnt  = (int*)(ws + 0);         // 392*4 B
    int*   bucket_base = (int*)(ws + 2048);      // 392*4 B
    int*   bcur        = (int*)(ws + 4096);      // 392*4 B
    float* dis         = (float*)(ws + 8192);    // 400000 B
    int*   row_start   = (int*)(ws + 408576);    // 400004 B
    int2*  pairs       = (int2*)(ws + 809472);   // 12.8 MB
    float* h           = (float*)(ws + 13609472);// 25.6 MB
    int2*  stage       = (int2*)(ws + 13609472); // aliases h (consumed before gemm1)
    float* a           = (float*)(ws + 39209472);// 25.6 MB  (total ~64.8 MB)

    const int* src = ei;
    const int* dst = ei + N_EDGES;

    int echunks = (N_EDGES + 4095) / 4096;   // 391

    hipMemsetAsync(bucket_cnt, 0, (NB + 1) * sizeof(int), stream);
    k_bhist<<<echunks, 256, 0, stream>>>(dst, bucket_cnt, N_EDGES);
    k_bscan<<<1, 64, 0, stream>>>(bucket_cnt, bucket_base, bcur, row_start);
    k_partA<<<echunks, 256, 0, stream>>>(src, dst, bcur, stage, N_EDGES);
    k_partB1<<<NB, 256, 0, stream>>>(stage, bucket_base, row_start, dis);
    k_partB2<<<NB, 256, 0, stream>>>(stage, bucket_base, row_start, dis, pairs);

    int gemm64 = (N_NODES + 63) / 64;      // BM=64 tiles
    int gemm32 = (N_NODES + 127) / 128;    // BM=128 tiles
    int aggblk = (N_NODES + 3) / 4;        // 1 node per wave, 4 waves/block

    // layer 1: 128 -> 64, relu
    k_gemm<128, 64><<<gemm64, 256, 0, stream>>>(x, W1, h, N_NODES);
    k_agg<64, true><<<aggblk, 256, 0, stream>>>(h, pairs, row_start, dis, b1, a, N_NODES);
    // layer 2: 64 -> 64, relu
    k_gemm<64, 64><<<gemm64, 256, 0, stream>>>(a, W2, h, N_NODES);
    k_agg<64, true><<<aggblk, 256, 0, stream>>>(h, pairs, row_start, dis, b2, a, N_NODES);
    // layer 3: 64 -> 32, no relu
    k_gemm<64, 32><<<gemm32, 256, 0, stream>>>(a, W3, h, N_NODES);
    k_agg<32, false><<<aggblk, 256, 0, stream>>>(h, pairs, row_start, dis, b3,
                                                 (float*)d_out, N_NODES);
}